// Round 8
// baseline (3997.340 us; speedup 1.0000x reference)
//
#include <hip/hip_runtime.h>
#include <math.h>

typedef _Float16 f16;
typedef _Float16 f16x8 __attribute__((ext_vector_type(8)));
typedef float f32x4 __attribute__((ext_vector_type(4)));

#define B_TOTAL 4096
#define T_STEPS 128
#define H 96
#define NB 16               // batch rows per block (one 16-row MFMA m-tile)
#define NTH 768             // 12 waves: group A = waves 0-5 (layers 0,2), B = 6-11 (layers 1,3)
#define NBLK (B_TOTAL / NB) // 256 blocks = 1 per CU

__device__ __forceinline__ float sigf(float v){ return 1.f/(1.f+__expf(-v)); }
__device__ __forceinline__ float tanhf_(float v){ float e=__expf(2.f*v); return 1.f-2.f/(e+1.f); }

// Load one layer's MFMA B-fragments: lane holds W[j=96q+u][k=32s+8*g4+e].
__device__ __forceinline__ void load_frags(f16x8 (&Bf)[4][6],
    const float* __restrict__ Wi, const float* __restrict__ Wh,
    int F, int KS, int u, int g4)
{
#pragma unroll
    for (int q=0;q<4;++q){
        int j = 96*q+u;
#pragma unroll
        for (int s=0;s<6;++s){
            f16x8 f = {0,0,0,0,0,0,0,0};
            if (s<KS){
#pragma unroll
                for (int e=0;e<8;++e){
                    int k = 32*s + 8*g4 + e;
                    float v = 0.f;
                    if (k<F)          v = Wi[(size_t)j*F+k];
                    else if (k-F<H)   v = Wh[(size_t)j*H+(k-F)];
                    f[e]=(f16)v;
                }
            }
            Bf[q][s]=f;
        }
    }
}

// One LSTM gate-GEMM + cell update for a 16-row tile.
// A-operand from LDS planes (hi + lo residual), B from VGPR frags.
// LO_S0: lo plane skipped for k-slices < LO_S0 (inter-layer input is pure f16).
template<int KS, int LO_S0, int KPB>
__device__ __forceinline__ void lstm_phase(const f16* bh, const f16* bl,
    const f16x8 (&Bf)[4][6], const float (&bq)[4],
    float (&c4)[4], float (&h4)[4], int j15, int g4)
{
    f32x4 acch[4], accl[4];
#pragma unroll
    for (int q=0;q<4;++q){
        f32x4 a={bq[q],bq[q],bq[q],bq[q]}; acch[q]=a;
        f32x4 z={0.f,0.f,0.f,0.f};          accl[q]=z;
    }
    const int abase = j15*KPB;
    const int aswz  = (j15&7)<<4;
#pragma unroll
    for (int s=0;s<KS;++s){
        int kb = ((s*64 + g4*16) ^ aswz);
        f16x8 ah = *(const f16x8*)((const char*)bh + abase + kb);
#pragma unroll
        for (int q=0;q<4;++q)
            acch[q]=__builtin_amdgcn_mfma_f32_16x16x32_f16(ah,Bf[q][s],acch[q],0,0,0);
        if (s>=LO_S0){
            f16x8 al = *(const f16x8*)((const char*)bl + abase + kb);
#pragma unroll
            for (int q=0;q<4;++q)
                accl[q]=__builtin_amdgcn_mfma_f32_16x16x32_f16(al,Bf[q][s],accl[q],0,0,0);
        }
    }
    // C[row][col]: col=lane&15 (unit), row=(lane>>4)*4+reg
#pragma unroll
    for (int r=0;r<4;++r){
        float iv=sigf(acch[0][r]+accl[0][r]);
        float fv=sigf(acch[1][r]+accl[1][r]);
        float gv=tanhf_(acch[2][r]+accl[2][r]);
        float ov=sigf(acch[3][r]+accl[3][r]);
        float c = fv*c4[r]+iv*gv;
        c4[r]=c;
        h4[r]=ov*tanhf_(c);
    }
}

// Write h (hi/lo) to own buffer's recurrent region; hi to next layer's input region.
template<int F, int KPB, bool HAS_NEXT>
__device__ __forceinline__ void lstm_write(f16* ohi, f16* olo, f16* nhi,
    const float (&h4)[4], int u, int g4)
{
#pragma unroll
    for (int r=0;r<4;++r){
        int row = 4*g4+r;
        float h = h4[r];
        f16 hh=(f16)h, hl=(f16)(h-(float)hh);
        int swz=(row&7)<<4;
        *(f16*)((char*)ohi + row*KPB + (((F+u)*2)^swz)) = hh;
        *(f16*)((char*)olo + row*KPB + (((F+u)*2)^swz)) = hl;
        if (HAS_NEXT)
            *(f16*)((char*)nhi + row*384 + ((u*2)^swz)) = hh;
    }
}

__global__ __launch_bounds__(NTH, 1)   // VGPR cap 512; 12 waves/CU needs <=682 -> safe
void lstm_net(const float* __restrict__ x,
              const float* __restrict__ W_ih0,
              const float* __restrict__ W_ih_rest,
              const float* __restrict__ W_hh,
              const float* __restrict__ b_ih,
              const float* __restrict__ b_hh,
              const float* __restrict__ fc1_w, const float* __restrict__ fc1_b,
              const float* __restrict__ fc2_w, const float* __restrict__ fc2_b,
              const float* __restrict__ fc3_w, const float* __restrict__ fc3_b,
              float* __restrict__ out)
{
    // per-layer A-operand buffers: [16 rows][KP] hi + lo planes
    __shared__ f16 b0h[16*128], b0l[16*128];   // layer0: K=24+96 -> KP 128
    __shared__ f16 b1h[16*192], b1l[16*192];   // layers 1-3: K=96+96 -> KP 192
    __shared__ f16 b2h[16*192], b2l[16*192];
    __shared__ f16 b3h[16*192], b3l[16*192];
    __shared__ float hsum[16*96];              // h1(T-1)+h3(T-1) for the head
    __shared__ float z1[16*16];
    __shared__ float z2[16*8];

    const int tid=threadIdx.x, lane=tid&63, w=tid>>6;
    const bool isA = (w<6);          // layers 0,2 ; else layers 1,3
    const int jg = isA ? w : w-6;    // unit group 0..5
    const int j15=lane&15, g4=lane>>4;
    const int u = 16*jg + j15;       // unit 0..95
    const int row0 = blockIdx.x*NB;

    for (int i=tid;i<16*128;i+=NTH){ b0h[i]=(f16)0.f; b0l[i]=(f16)0.f; }
    for (int i=tid;i<16*192;i+=NTH){
        b1h[i]=(f16)0.f; b1l[i]=(f16)0.f;
        b2h[i]=(f16)0.f; b2l[i]=(f16)0.f;
        b3h[i]=(f16)0.f; b3l[i]=(f16)0.f;
    }

    // weight fragments: each wave holds TWO layers (union across groups = 192 VGPR)
    const int GH = 384*96;
    const float *WiX,*WhX,*biX,*bhX,*WiY,*WhY,*biY,*bhY; int FX,KSX;
    if (isA){ WiX=W_ih0;           WhX=W_hh;        biX=b_ih;        bhX=b_hh;        FX=24; KSX=4;
              WiY=W_ih_rest+GH;    WhY=W_hh+2*GH;   biY=b_ih+2*384;  bhY=b_hh+2*384; }
    else    { WiX=W_ih_rest;       WhX=W_hh+GH;     biX=b_ih+384;    bhX=b_hh+384;    FX=96; KSX=6;
              WiY=W_ih_rest+2*GH;  WhY=W_hh+3*GH;   biY=b_ih+3*384;  bhY=b_hh+3*384; }

    f16x8 BfX[4][6], BfY[4][6];
    load_frags(BfX, WiX, WhX, FX, KSX, u, g4);
    load_frags(BfY, WiY, WhY, 96, 6,  u, g4);
    float bqX[4], bqY[4];
#pragma unroll
    for (int q=0;q<4;++q){ bqX[q]=biX[96*q+u]+bhX[96*q+u]; bqY[q]=biY[96*q+u]+bhY[96*q+u]; }

    float cX[4]={0.f,0.f,0.f,0.f}, cY[4]={0.f,0.f,0.f,0.f}, h4[4];

    // x staging mapping (group B: 384 threads = 16 rows x 24 feats, one f32 each)
    const int tb = (tid>=384)? tid-384 : 0;
    const int xr = tb/24, xk = tb - xr*24;
    const float* xbase = x + (size_t)(row0+xr)*(T_STEPS*24) + xk;
    const int xoffb = xr*256 + ((xk*2)^((xr&7)<<4));

    __syncthreads();
    if (!isA){ // stage x(0)
        float v = xbase[0];
        f16 vh=(f16)v, vl=(f16)(v-(float)vh);
        *(f16*)((char*)b0h+xoffb)=vh; *(f16*)((char*)b0l+xoffb)=vl;
    }
    __syncthreads();

#pragma unroll 1
    for (int t=0;t<T_STEPS;++t){
        // issue x(t+1) load early; latency hides under P0 compute
        float xv = 0.f;
        if (!isA && t+1<T_STEPS) xv = xbase[(size_t)(t+1)*24];

        // ---- P0: layer 0 (A) ---- (B's P3-write of t-1 overlaps here)
        if (isA) lstm_phase<4,0,256>(b0h,b0l,BfX,bqX,cX,h4,j15,g4);
        __syncthreads();
        if (isA) lstm_write<24,256,true>(b0h,b0l,b1h,h4,u,g4);
        else if (t+1<T_STEPS){ // stage x(t+1) into b0 input region
            f16 vh=(f16)xv, vl=(f16)(xv-(float)vh);
            *(f16*)((char*)b0h+xoffb)=vh; *(f16*)((char*)b0l+xoffb)=vl;
        }
        __syncthreads();
        // ---- P1: layer 1 (B) ----
        if (!isA) lstm_phase<6,3,384>(b1h,b1l,BfX,bqX,cX,h4,j15,g4);
        __syncthreads();
        if (!isA){
            lstm_write<96,384,true>(b1h,b1l,b2h,h4,u,g4);
            if (t==T_STEPS-1){
#pragma unroll
                for (int r=0;r<4;++r) hsum[(4*g4+r)*96+u]=h4[r];
            }
        }
        __syncthreads();
        // ---- P2: layer 2 (A) ----
        if (isA) lstm_phase<6,3,384>(b2h,b2l,BfY,bqY,cY,h4,j15,g4);
        __syncthreads();
        if (isA) lstm_write<96,384,true>(b2h,b2l,b3h,h4,u,g4);
        __syncthreads();
        // ---- P3: layer 3 (B) ----
        if (!isA) lstm_phase<6,3,384>(b3h,b3l,BfY,bqY,cY,h4,j15,g4);
        __syncthreads();
        if (!isA){
            lstm_write<96,384,false>(b3h,b3l,nullptr,h4,u,g4);
            if (t==T_STEPS-1){
#pragma unroll
                for (int r=0;r<4;++r) hsum[(4*g4+r)*96+u]+=h4[r];
            }
        }
        // no trailing barrier: next P0 reads only b0 (fenced by the P1 barrier),
        // and b3/hsum writes are fenced from their next readers by >=2 barriers.
    }
    __syncthreads();

    // ---- fused head: relu(hsum) -> fc1 -> relu -> fc2 -> relu -> fc3 ----
    if (tid<256){
        int r=tid>>4, jj=tid&15;
        float a=fc1_b[jj];
        for (int uu=0;uu<96;++uu) a += fc1_w[jj*96+uu]*fmaxf(hsum[r*96+uu],0.f);
        z1[r*16+jj]=fmaxf(a,0.f);
    }
    __syncthreads();
    if (tid<128){
        int r=tid>>3, jj=tid&7;
        float a=fc2_b[jj];
#pragma unroll
        for (int uu=0;uu<16;++uu) a += fc2_w[jj*16+uu]*z1[r*16+uu];
        z2[r*8+jj]=fmaxf(a,0.f);
    }
    __syncthreads();
    if (tid<16){
        float a=fc3_b[0];
#pragma unroll
        for (int uu=0;uu<8;++uu) a += fc3_w[uu]*z2[tid*8+uu];
        out[row0+tid]=a;
    }
}

extern "C" void kernel_launch(void* const* d_in, const int* in_sizes, int n_in,
                              void* d_out, int out_size, void* d_ws, size_t ws_size,
                              hipStream_t stream) {
    const float* x         = (const float*)d_in[0];
    const float* W_ih0     = (const float*)d_in[1];
    const float* W_ih_rest = (const float*)d_in[2];
    const float* W_hh      = (const float*)d_in[3];
    const float* b_ih      = (const float*)d_in[4];
    const float* b_hh      = (const float*)d_in[5];
    const float* fc1_w     = (const float*)d_in[6];
    const float* fc1_b     = (const float*)d_in[7];
    const float* fc2_w     = (const float*)d_in[8];
    const float* fc2_b     = (const float*)d_in[9];
    const float* fc3_w     = (const float*)d_in[10];
    const float* fc3_b     = (const float*)d_in[11];
    float* out = (float*)d_out;

    lstm_net<<<dim3(NBLK), dim3(NTH), 0, stream>>>(
        x, W_ih0, W_ih_rest, W_hh, b_ih, b_hh,
        fc1_w, fc1_b, fc2_w, fc2_b, fc3_w, fc3_b, out);
}

// Round 9
// 1630.789 us; speedup vs baseline: 2.4512x; 2.4512x over previous
//
#include <hip/hip_runtime.h>
#include <math.h>

typedef _Float16 f16;
typedef _Float16 f16x8 __attribute__((ext_vector_type(8)));
typedef float f32x4 __attribute__((ext_vector_type(4)));

#define B_TOTAL 4096
#define T_STEPS 128
#define H 96
#define NB 16               // batch rows per block (one 16-row MFMA m-tile)
#define NTH 768             // 12 waves: group A = waves 0-5, group B = waves 6-11
#define NBLK (B_TOTAL / NB) // 256 blocks = 1 per CU

__device__ __forceinline__ float sigf(float v){ return 1.f/(1.f+__expf(-v)); }
__device__ __forceinline__ float tanhf_(float v){ float e=__expf(2.f*v); return 1.f-2.f/(e+1.f); }

// One layer's MFMA B-fragments: lane holds W[j=96q+u][k=32s+8*g4+e].
// ONE array per wave (<=96 VGPR) — the compiler-proven no-spill budget.
template<int F, int KS>
__device__ __forceinline__ void load_frags(f16x8 (&Bf)[4][6],
    const float* __restrict__ Wi, const float* __restrict__ Wh, int u, int g4)
{
#pragma unroll
    for (int q=0;q<4;++q){
        int j = 96*q+u;
#pragma unroll
        for (int s=0;s<KS;++s){
            f16x8 f;
#pragma unroll
            for (int e=0;e<8;++e){
                int k = 32*s + 8*g4 + e;
                float v = 0.f;
                if (k<F)          v = Wi[(size_t)j*F+k];
                else if (k-F<H)   v = Wh[(size_t)j*H+(k-F)];
                f[e]=(f16)v;
            }
            Bf[q][s]=f;
        }
    }
}

// Gate-GEMM + cell update for a 16-row tile (validated layout/numerics).
template<int KS, int LO_S0, int KPB>
__device__ __forceinline__ void lstm_phase(const f16* bh, const f16* bl,
    const f16x8 (&Bf)[4][6], const float (&bq)[4],
    float (&c4)[4], float (&h4)[4], int j15, int g4)
{
    f32x4 acch[4], accl[4];
#pragma unroll
    for (int q=0;q<4;++q){
        f32x4 a={bq[q],bq[q],bq[q],bq[q]}; acch[q]=a;
        f32x4 z={0.f,0.f,0.f,0.f};          accl[q]=z;
    }
    const int abase = j15*KPB;
    const int aswz  = (j15&7)<<4;
#pragma unroll
    for (int s=0;s<KS;++s){
        int kb = ((s*64 + g4*16) ^ aswz);
        f16x8 ah = *(const f16x8*)((const char*)bh + abase + kb);
#pragma unroll
        for (int q=0;q<4;++q)
            acch[q]=__builtin_amdgcn_mfma_f32_16x16x32_f16(ah,Bf[q][s],acch[q],0,0,0);
        if (s>=LO_S0){
            f16x8 al = *(const f16x8*)((const char*)bl + abase + kb);
#pragma unroll
            for (int q=0;q<4;++q)
                accl[q]=__builtin_amdgcn_mfma_f32_16x16x32_f16(al,Bf[q][s],accl[q],0,0,0);
        }
    }
#pragma unroll
    for (int r=0;r<4;++r){
        float iv=sigf(acch[0][r]+accl[0][r]);
        float fv=sigf(acch[1][r]+accl[1][r]);
        float gv=tanhf_(acch[2][r]+accl[2][r]);
        float ov=sigf(acch[3][r]+accl[3][r]);
        float c = fv*c4[r]+iv*gv;
        c4[r]=c;
        h4[r]=ov*tanhf_(c);
    }
}

// Two layers per kernel, STAGGERED: group A computes layer_A(t) while group B
// computes layer_B(t-1). Handoff h_A -> layer_B input via double-buffered LDS
// (bB[2]); A's own input buffer bA is single (write-after-read, barrier-safe).
// FIRST: A=layer0 (x input, hi/lo), B=layer1 (stores ys + hn1).
// !FIRST: A=layer2 (ys input), B=layer3 (head fused at the end).
template<bool FIRST>
__global__ __launch_bounds__(NTH, 2)
void lstm_pair(const float* __restrict__ x,
               f16* __restrict__ ys,            // FIRST: out; !FIRST: in
               const float* __restrict__ WiA, const float* __restrict__ WhA,
               const float* __restrict__ biA, const float* __restrict__ bhA,
               const float* __restrict__ WiB, const float* __restrict__ WhB,
               const float* __restrict__ biB, const float* __restrict__ bhB,
               float* __restrict__ hn1g,        // FIRST: out; !FIRST: in
               const float* __restrict__ fc1_w, const float* __restrict__ fc1_b,
               const float* __restrict__ fc2_w, const float* __restrict__ fc2_b,
               const float* __restrict__ fc3_w, const float* __restrict__ fc3_b,
               float* __restrict__ out)
{
    constexpr int KSA  = FIRST ? 4 : 6;
    constexpr int LOA  = FIRST ? 0 : 3;   // x has lo plane; ys relay is f16-only
    constexpr int KPBA = KSA*32*2;        // bytes per A-buffer row
    constexpr int FA   = FIRST ? 24 : 96;

    __shared__ f16 bAh[16*192], bAl[16*192];
    __shared__ f16 bBh[2][16*192], bBl[2][16*192];
    __shared__ float hsum[16*96];
    __shared__ float z1[16*16];
    __shared__ float z2[16*8];

    const int tid=threadIdx.x, lane=tid&63, w=tid>>6;
    const bool isA = (w<6);
    const int jg = isA ? w : w-6;
    const int j15=lane&15, g4=lane>>4;
    const int u = 16*jg + j15;
    const int row0 = blockIdx.x*NB;

    for (int i=tid;i<16*192;i+=NTH){
        bAh[i]=(f16)0.f; bAl[i]=(f16)0.f;
        bBh[0][i]=(f16)0.f; bBl[0][i]=(f16)0.f;
        bBh[1][i]=(f16)0.f; bBl[1][i]=(f16)0.f;
    }

    // ONE fragment array + ONE bias vector per thread (group-dependent weights)
    f16x8 Bf[4][6];
    float bq[4];
    if (isA){
        load_frags<FA,KSA>(Bf, WiA, WhA, u, g4);
#pragma unroll
        for (int q=0;q<4;++q) bq[q]=biA[96*q+u]+bhA[96*q+u];
    } else {
        load_frags<96,6>(Bf, WiB, WhB, u, g4);
#pragma unroll
        for (int q=0;q<4;++q) bq[q]=biB[96*q+u]+bhB[96*q+u];
    }
    float c4[4]={0.f,0.f,0.f,0.f}, h4[4];

    // input staging maps
    const int tb = tid>=384 ? tid-384 : 0;           // FIRST: B-threads stage x
    const int xr = tb/24, xk = tb-xr*24;
    const float* xbase = FIRST ? x+(size_t)(row0+xr)*(T_STEPS*24)+xk : nullptr;
    const int xoff = xr*KPBA + ((xk*2)^((xr&7)<<4));

    const int yi = tid*4;                            // !FIRST: tid<384 stage ys
    const int yr = yi/96, yk = yi-yr*96;
    const int yoff = yr*KPBA + ((yk*2)^((yr&7)<<4));

    __syncthreads();
    if constexpr (FIRST){
        if (!isA){
            float v = xbase[0];
            f16 vh=(f16)v, vl=(f16)(v-(float)vh);
            *(f16*)((char*)bAh+xoff)=vh; *(f16*)((char*)bAl+xoff)=vl;
        }
    } else {
        if (tid<384){
            uint2 v = *(const uint2*)(ys + ((size_t)(row0+yr))*96 + yk);
            *(uint2*)((char*)bAh+yoff)=v;
        }
    }
    __syncthreads();

#pragma unroll 1
    for (int s=0;s<=T_STEPS;++s){
        // issue next-step input loads early; latency hides under compute
        float xv = 0.f; uint2 yv = {0u,0u};
        if constexpr (FIRST){
            if (!isA && s+1<T_STEPS) xv = xbase[(size_t)(s+1)*24];
        } else {
            if (tid<384 && s+1<T_STEPS)
                yv = *(const uint2*)(ys + ((size_t)(s+1)*B_TOTAL + row0+yr)*96 + yk);
        }

        // ---- concurrent compute: A on t=s, B on t=s-1 ----
        if (isA && s<T_STEPS)
            lstm_phase<KSA,LOA,KPBA>(bAh,bAl,Bf,bq,c4,h4,j15,g4);
        if (!isA && s>0)
            lstm_phase<6,3,384>(bBh[(s-1)&1],bBl[(s-1)&1],Bf,bq,c4,h4,j15,g4);
        __syncthreads();

        // ---- write phase (disjoint LDS regions) ----
        if (isA && s<T_STEPS){
            f16* nh = bBh[s&1];
#pragma unroll
            for (int r=0;r<4;++r){
                int row=4*g4+r, swz=(row&7)<<4;
                float h=h4[r]; f16 hh=(f16)h, hl=(f16)(h-(float)hh);
                *(f16*)((char*)bAh + row*KPBA + (((FA+u)*2)^swz)) = hh;
                *(f16*)((char*)bAl + row*KPBA + (((FA+u)*2)^swz)) = hl;
                *(f16*)((char*)nh  + row*384  + ((u*2)^swz))      = hh; // handoff (f16-only)
            }
        }
        if (!isA && s>0){
            const int t=s-1;
            f16* oh=bBh[s&1]; f16* ol=bBl[s&1];
#pragma unroll
            for (int r=0;r<4;++r){
                int row=4*g4+r, swz=(row&7)<<4;
                float h=h4[r]; f16 hh=(f16)h, hl=(f16)(h-(float)hh);
                *(f16*)((char*)oh + row*384 + (((96+u)*2)^swz)) = hh;
                *(f16*)((char*)ol + row*384 + (((96+u)*2)^swz)) = hl;
                if constexpr (FIRST){
                    ys[((size_t)t*B_TOTAL + row0+row)*96 + u] = hh;
                    if (t==T_STEPS-1) hn1g[(size_t)(row0+row)*96+u] = h;
                } else {
                    if (t==T_STEPS-1) hsum[row*96+u] = h;
                }
            }
        }
        // stage next input into bA's input region
        if constexpr (FIRST){
            if (!isA && s+1<T_STEPS){
                f16 vh=(f16)xv, vl=(f16)(xv-(float)vh);
                *(f16*)((char*)bAh+xoff)=vh; *(f16*)((char*)bAl+xoff)=vl;
            }
        } else {
            if (tid<384 && s+1<T_STEPS)
                *(uint2*)((char*)bAh+yoff)=yv;
        }
        __syncthreads();
    }

    if constexpr (!FIRST){
        // hsum = h3(T-1) (in LDS) + hn1 (global), then fused MLP head
        if (tid<384){
            float4 v = *(const float4*)(hn1g + (size_t)row0*96 + tid*4);
            hsum[tid*4+0]+=v.x; hsum[tid*4+1]+=v.y;
            hsum[tid*4+2]+=v.z; hsum[tid*4+3]+=v.w;
        }
        __syncthreads();
        if (tid<256){
            int r=tid>>4, jj=tid&15;
            float a=fc1_b[jj];
            for (int uu=0;uu<96;++uu) a += fc1_w[jj*96+uu]*fmaxf(hsum[r*96+uu],0.f);
            z1[r*16+jj]=fmaxf(a,0.f);
        }
        __syncthreads();
        if (tid<128){
            int r=tid>>3, jj=tid&7;
            float a=fc2_b[jj];
#pragma unroll
            for (int uu=0;uu<16;++uu) a += fc2_w[jj*16+uu]*z1[r*16+uu];
            z2[r*8+jj]=fmaxf(a,0.f);
        }
        __syncthreads();
        if (tid<16){
            float a=fc3_b[0];
#pragma unroll
            for (int uu=0;uu<8;++uu) a += fc3_w[uu]*z2[tid*8+uu];
            out[row0+tid]=a;
        }
    }
}

extern "C" void kernel_launch(void* const* d_in, const int* in_sizes, int n_in,
                              void* d_out, int out_size, void* d_ws, size_t ws_size,
                              hipStream_t stream) {
    const float* x         = (const float*)d_in[0];
    const float* W_ih0     = (const float*)d_in[1];
    const float* W_ih_rest = (const float*)d_in[2];
    const float* W_hh      = (const float*)d_in[3];
    const float* b_ih      = (const float*)d_in[4];
    const float* b_hh      = (const float*)d_in[5];
    const float* fc1_w     = (const float*)d_in[6];
    const float* fc1_b     = (const float*)d_in[7];
    const float* fc2_w     = (const float*)d_in[8];
    const float* fc2_b     = (const float*)d_in[9];
    const float* fc3_w     = (const float*)d_in[10];
    const float* fc3_b     = (const float*)d_in[11];
    float* out = (float*)d_out;

    const size_t YS = (size_t)T_STEPS * B_TOTAL * H * sizeof(f16);   // ~100.7 MB
    const size_t HN = (size_t)B_TOTAL * H * sizeof(float);           // ~1.6 MB
    if (ws_size < YS + HN) {
        hipMemsetAsync(d_out, 0, (size_t)out_size * sizeof(float), stream);
        return;
    }
    f16*   ys   = (f16*)d_ws;
    float* hn1g = (float*)((char*)d_ws + YS);

    const int GH = 384 * 96;

    // kernel 1: layers 0 (A) || 1 (B), staggered by one timestep
    lstm_pair<true><<<dim3(NBLK), dim3(NTH), 0, stream>>>(
        x, ys,
        W_ih0,              W_hh,        b_ih,          b_hh,
        W_ih_rest,          W_hh + GH,   b_ih + 384,    b_hh + 384,
        hn1g,
        fc1_w, fc1_b, fc2_w, fc2_b, fc3_w, fc3_b, out);

    // kernel 2: layers 2 (A) || 3 (B), staggered; head fused
    lstm_pair<false><<<dim3(NBLK), dim3(NTH), 0, stream>>>(
        nullptr, ys,
        W_ih_rest + GH,     W_hh + 2*GH, b_ih + 2*384,  b_hh + 2*384,
        W_ih_rest + 2*GH,   W_hh + 3*GH, b_ih + 3*384,  b_hh + 3*384,
        hn1g,
        fc1_w, fc1_b, fc2_w, fc2_b, fc3_w, fc3_b, out);
}

// Round 10
// 1028.038 us; speedup vs baseline: 3.8883x; 1.5863x over previous
//
#include <hip/hip_runtime.h>
#include <math.h>

typedef _Float16 f16;
typedef _Float16 f16x8 __attribute__((ext_vector_type(8)));
typedef float f32x4 __attribute__((ext_vector_type(4)));

#define B_TOTAL 4096
#define T_STEPS 128
#define H 96
#define NB 16               // batch rows per block (one 16-row MFMA m-tile)
#define NTH 384             // 6 waves — the proven no-spill shape
#define NBLK (B_TOTAL/NB)   // 256 blocks = 1 per CU

__device__ __forceinline__ float sigf(float v){ return 1.f/(1.f+__expf(-v)); }
__device__ __forceinline__ float tanhf_(float v){ float e=__expf(2.f*v); return 1.f-2.f/(e+1.f); }

// One LSTM layer, sequential (one kernel per layer). Single barrier per step:
// step t reads act buffer[t&1], writes h(t) and staged input(t+1) into
// buffer[1-(t&1)] — read/write phases touch different buffers, so only the
// end-of-step barrier is needed. Next-step global input is issued at the TOP
// of the step (T14) and consumed into LDS at the end.
template<int F, bool IS_L0, bool HAS_YSOUT, bool WRITE_HN, bool IS_LAST>
__global__ __launch_bounds__(NTH, 2)   // cap 256 VGPR — proven no-spill budget
void lstm_seq(const float* __restrict__ x,     // IS_L0 input
              f16* __restrict__ ys,            // relay [T][B][H] f16 (in/out)
              const float* __restrict__ Wi, const float* __restrict__ Wh,
              const float* __restrict__ bi, const float* __restrict__ bh,
              float* __restrict__ hn1g,        // WRITE_HN: store; IS_LAST: load
              const float* __restrict__ fc1_w, const float* __restrict__ fc1_b,
              const float* __restrict__ fc2_w, const float* __restrict__ fc2_b,
              const float* __restrict__ fc3_w, const float* __restrict__ fc3_b,
              float* __restrict__ out)
{
    constexpr int KS  = (F + H + 31)/32;   // 4 (F=24) or 6 (F=96)
    constexpr int KP  = KS*32;
    constexpr int KPB = KP*2;              // bytes per act row
    constexpr int LO0 = IS_L0 ? 0 : 3;     // ys relay is pure f16 -> skip lo input slices
    constexpr int BUF = 16*KP;             // halves per plane per buffer

    __shared__ f16 sh[2*BUF], sl[2*BUF];   // hi/lo planes, double-buffered
    __shared__ float hsum[16*96];          // head scratch (used only IS_LAST)
    __shared__ float z1[16*16];
    __shared__ float z2[16*8];

    const int tid=threadIdx.x, lane=tid&63, w=tid>>6;
    const int j15=lane&15, g4=lane>>4;
    const int u=16*w+j15;                  // unit 0..95
    const int row0=blockIdx.x*NB;

    for (int i=tid;i<2*BUF;i+=NTH){ sh[i]=(f16)0.f; sl[i]=(f16)0.f; }

    // weight B-frags, loaded once: lane holds W[j=96q+u][k=32s+8*g4+e]
    f16x8 Bf[4][KS];
#pragma unroll
    for (int q=0;q<4;++q){
        const int j=96*q+u;
#pragma unroll
        for (int s=0;s<KS;++s){
            f16x8 f;
#pragma unroll
            for (int e=0;e<8;++e){
                int k=32*s+8*g4+e;
                float v=0.f;
                if (k<F)        v=Wi[(size_t)j*F+k];
                else if (k-F<H) v=Wh[(size_t)j*H+(k-F)];
                f[e]=(f16)v;
            }
            Bf[q][s]=f;
        }
    }
    float bq[4];
#pragma unroll
    for (int q=0;q<4;++q) bq[q]=bi[96*q+u]+bh[96*q+u];

    float c4[4]={0.f,0.f,0.f,0.f}, h4[4]={0.f,0.f,0.f,0.f};

    // staging maps
    const int xr=tid/24, xk=tid-xr*24;     // IS_L0: 384 thr = 16 rows x 24 feats
    const float* xbase = IS_L0 ? x + (size_t)(row0+xr)*(T_STEPS*24) + xk : nullptr;
    const int xoff = xr*KPB + ((xk*2)^((xr&7)<<4));

    const int yi=tid*4, yr=yi/H, yk=yi-yr*H;   // else: 16 rows x 96 halves, uint2 each
    const f16* ybase = (!IS_L0) ? ys + (size_t)(row0+yr)*H + yk : nullptr;
    const int yoff = yr*KPB + ((yk*2)^((yr&7)<<4));

    // stage t=0 into buffer 0
    if constexpr (IS_L0){
        float v=xbase[0];
        f16 vh=(f16)v, vl=(f16)(v-(float)vh);
        *(f16*)((char*)sh+xoff)=vh; *(f16*)((char*)sl+xoff)=vl;
    } else {
        uint2 v=*(const uint2*)(ybase);
        *(uint2*)((char*)sh+yoff)=v;
    }
    __syncthreads();

    const int aswz=(j15&7)<<4;
    const int abase=j15*KPB;

#pragma unroll 1
    for (int t=0;t<T_STEPS;++t){
        const int cur=t&1, nxt=cur^1;
        const f16* ch=sh+cur*BUF; const f16* cl=sl+cur*BUF;
        f16*       nh=sh+nxt*BUF; f16*       nl=sl+nxt*BUF;

        // T14: issue next-step global input load NOW; consumed at step end
        float xv=0.f; uint2 yv={0u,0u};
        if (t+1<T_STEPS){
            if constexpr (IS_L0) xv = xbase[(size_t)(t+1)*24];
            else                 yv = *(const uint2*)(ybase + (size_t)(t+1)*B_TOTAL*H);
        }

        // ---- gate GEMM (reads buf[cur] only) ----
        f32x4 acch[4], accl[4];
#pragma unroll
        for (int q=0;q<4;++q){
            f32x4 a={bq[q],bq[q],bq[q],bq[q]}; acch[q]=a;
            f32x4 z={0.f,0.f,0.f,0.f};          accl[q]=z;
        }
#pragma unroll
        for (int s=0;s<KS;++s){
            int kb=((s*64+g4*16)^aswz);
            f16x8 ah=*(const f16x8*)((const char*)ch+abase+kb);
#pragma unroll
            for (int q=0;q<4;++q)
                acch[q]=__builtin_amdgcn_mfma_f32_16x16x32_f16(ah,Bf[q][s],acch[q],0,0,0);
            if (s>=LO0){
                f16x8 al=*(const f16x8*)((const char*)cl+abase+kb);
#pragma unroll
                for (int q=0;q<4;++q)
                    accl[q]=__builtin_amdgcn_mfma_f32_16x16x32_f16(al,Bf[q][s],accl[q],0,0,0);
            }
        }
        // ---- cell update (registers) ----
#pragma unroll
        for (int r=0;r<4;++r){
            float iv=sigf(acch[0][r]+accl[0][r]);
            float fv=sigf(acch[1][r]+accl[1][r]);
            float gv=tanhf_(acch[2][r]+accl[2][r]);
            float ov=sigf(acch[3][r]+accl[3][r]);
            float c=fv*c4[r]+iv*gv;
            c4[r]=c;
            h4[r]=ov*tanhf_(c);
        }
        // ---- h -> buf[nxt] (+ ys / hn / hsum) ----
#pragma unroll
        for (int r=0;r<4;++r){
            int row=4*g4+r, swz=(row&7)<<4;
            float h=h4[r];
            f16 hh=(f16)h, hl=(f16)(h-(float)hh);
            if constexpr (HAS_YSOUT)
                ys[((size_t)t*B_TOTAL+row0+row)*H+u]=hh;   // issue early: drains under rest
            *(f16*)((char*)nh + row*KPB + (((F+u)*2)^swz)) = hh;
            *(f16*)((char*)nl + row*KPB + (((F+u)*2)^swz)) = hl;
            if constexpr (WRITE_HN){ if (t==T_STEPS-1) hn1g[(size_t)(row0+row)*H+u]=h; }
            if constexpr (IS_LAST) { if (t==T_STEPS-1) hsum[row*96+u]=h; }
        }
        // ---- staged input -> buf[nxt] ----
        if (t+1<T_STEPS){
            if constexpr (IS_L0){
                f16 vh=(f16)xv, vl=(f16)(xv-(float)vh);
                *(f16*)((char*)nh+xoff)=vh; *(f16*)((char*)nl+xoff)=vl;
            } else {
                *(uint2*)((char*)nh+yoff)=yv;
            }
        }
        __syncthreads();   // the ONLY barrier per step
    }

    if constexpr (IS_LAST){
        // hsum = h3(T-1) + hn1 (global, from layer-1 kernel), then fused head
        {
            float4 v=*(const float4*)(hn1g + (size_t)row0*96 + tid*4);
            hsum[tid*4+0]+=v.x; hsum[tid*4+1]+=v.y;
            hsum[tid*4+2]+=v.z; hsum[tid*4+3]+=v.w;
        }
        __syncthreads();
        if (tid<256){
            int r=tid>>4, jj=tid&15;
            float a=fc1_b[jj];
            for (int uu=0;uu<96;++uu) a+=fc1_w[jj*96+uu]*fmaxf(hsum[r*96+uu],0.f);
            z1[r*16+jj]=fmaxf(a,0.f);
        }
        __syncthreads();
        if (tid<128){
            int r=tid>>3, jj=tid&7;
            float a=fc2_b[jj];
#pragma unroll
            for (int uu=0;uu<16;++uu) a+=fc2_w[jj*16+uu]*z1[r*16+uu];
            z2[r*8+jj]=fmaxf(a,0.f);
        }
        __syncthreads();
        if (tid<16){
            float a=fc3_b[0];
#pragma unroll
            for (int uu=0;uu<8;++uu) a+=fc3_w[uu]*z2[tid*8+uu];
            out[row0+tid]=a;
        }
    }
}

extern "C" void kernel_launch(void* const* d_in, const int* in_sizes, int n_in,
                              void* d_out, int out_size, void* d_ws, size_t ws_size,
                              hipStream_t stream) {
    const float* x         = (const float*)d_in[0];
    const float* W_ih0     = (const float*)d_in[1];
    const float* W_ih_rest = (const float*)d_in[2];
    const float* W_hh      = (const float*)d_in[3];
    const float* b_ih      = (const float*)d_in[4];
    const float* b_hh      = (const float*)d_in[5];
    const float* fc1_w     = (const float*)d_in[6];
    const float* fc1_b     = (const float*)d_in[7];
    const float* fc2_w     = (const float*)d_in[8];
    const float* fc2_b     = (const float*)d_in[9];
    const float* fc3_w     = (const float*)d_in[10];
    const float* fc3_b     = (const float*)d_in[11];
    float* out = (float*)d_out;

    const size_t YS = (size_t)T_STEPS * B_TOTAL * H * sizeof(f16);   // ~100.7 MB
    const size_t HN = (size_t)B_TOTAL * H * sizeof(float);           // ~1.6 MB
    if (ws_size < YS + HN) {
        hipMemsetAsync(d_out, 0, (size_t)out_size * sizeof(float), stream);
        return;
    }
    f16*   ys   = (f16*)d_ws;
    float* hn1g = (float*)((char*)d_ws + YS);

    const int GH = 384 * 96;

    // layer 0: x -> ys
    lstm_seq<24, true,  true,  false, false><<<NBLK, NTH, 0, stream>>>(
        x, ys, W_ih0, W_hh, b_ih, b_hh, hn1g,
        fc1_w, fc1_b, fc2_w, fc2_b, fc3_w, fc3_b, out);
    // layer 1: ys -> ys (in-place), hn1 -> global
    lstm_seq<96, false, true,  true,  false><<<NBLK, NTH, 0, stream>>>(
        nullptr, ys, W_ih_rest,        W_hh + 1*GH, b_ih + 1*384, b_hh + 1*384, hn1g,
        fc1_w, fc1_b, fc2_w, fc2_b, fc3_w, fc3_b, out);
    // layer 2: ys -> ys
    lstm_seq<96, false, true,  false, false><<<NBLK, NTH, 0, stream>>>(
        nullptr, ys, W_ih_rest + 1*GH, W_hh + 2*GH, b_ih + 2*384, b_hh + 2*384, hn1g,
        fc1_w, fc1_b, fc2_w, fc2_b, fc3_w, fc3_b, out);
    // layer 3: ys -> (head fused) -> out
    lstm_seq<96, false, false, false, true ><<<NBLK, NTH, 0, stream>>>(
        nullptr, ys, W_ih_rest + 2*GH, W_hh + 3*GH, b_ih + 3*384, b_hh + 3*384, hn1g,
        fc1_w, fc1_b, fc2_w, fc2_b, fc3_w, fc3_b, out);
}

// Round 11
// 920.842 us; speedup vs baseline: 4.3410x; 1.1164x over previous
//
#include <hip/hip_runtime.h>
#include <math.h>

typedef _Float16 f16;
typedef _Float16 f16x8 __attribute__((ext_vector_type(8)));
typedef float f32x4 __attribute__((ext_vector_type(4)));

#define B_TOTAL 4096
#define T_STEPS 128
#define H 96
#define NB 16               // batch rows per block (one 16-row MFMA m-tile)
#define NTH 384             // 6 waves — the proven no-spill shape
#define NBLK (B_TOTAL/NB)   // 256 blocks = 1 per CU

__device__ __forceinline__ float sigf(float v){ return 1.f/(1.f+__expf(-v)); }
__device__ __forceinline__ float tanhf_(float v){ float e=__expf(2.f*v); return 1.f-2.f/(e+1.f); }

// One LSTM layer per kernel, sequential over T, single barrier per step.
// vs round 10:
//  - recurrent h is f16-only (lo residual dropped; ys transport was already
//    f16-only at absmax 6.1e-5). Lo plane exists only for layer 0's x (slice 0).
//  - gate accumulators split by slice parity (acch/accl) -> MFMA chain depth 3.
//  - ys store delayed one step (h4p regs): vmcnt drain never on the chain.
template<int F, bool IS_L0, bool HAS_YSOUT, bool WRITE_HN, bool IS_LAST>
__global__ __launch_bounds__(NTH, 2)   // cap 256 VGPR — proven no-spill budget
void lstm_seq(const float* __restrict__ x,     // IS_L0 input
              f16* __restrict__ ys,            // relay [T][B][H] f16 (in/out)
              const float* __restrict__ Wi, const float* __restrict__ Wh,
              const float* __restrict__ bi, const float* __restrict__ bh,
              float* __restrict__ hn1g,        // WRITE_HN: store; IS_LAST: load
              const float* __restrict__ fc1_w, const float* __restrict__ fc1_b,
              const float* __restrict__ fc2_w, const float* __restrict__ fc2_b,
              const float* __restrict__ fc3_w, const float* __restrict__ fc3_b,
              float* __restrict__ out)
{
    constexpr int  KS   = (F + H + 31)/32;   // 4 (F=24) or 6 (F=96)
    constexpr int  KP   = KS*32;
    constexpr int  KPB  = KP*2;              // bytes per act row
    constexpr bool HAS_LO = IS_L0;           // lo plane only for x (slice 0)
    constexpr int  BUF  = 16*KP;

    __shared__ f16 sh[2*BUF];                    // hi plane, double-buffered
    __shared__ f16 sl[HAS_LO ? 2*BUF : 64];      // lo plane (L0 only)
    __shared__ float hsum[16*96];                // head scratch (IS_LAST)
    __shared__ float z1[16*16];
    __shared__ float z2[16*8];

    const int tid=threadIdx.x, lane=tid&63, w=tid>>6;
    const int j15=lane&15, g4=lane>>4;
    const int u=16*w+j15;                        // unit 0..95
    const int row0=blockIdx.x*NB;

    for (int i=tid;i<2*BUF;i+=NTH) sh[i]=(f16)0.f;
    if constexpr (HAS_LO)
        for (int i=tid;i<2*BUF;i+=NTH) sl[i]=(f16)0.f;

    // weight B-frags, loaded once: lane holds W[j=96q+u][k=32s+8*g4+e]
    f16x8 Bf[4][KS];
#pragma unroll
    for (int q=0;q<4;++q){
        const int j=96*q+u;
#pragma unroll
        for (int s=0;s<KS;++s){
            f16x8 f;
#pragma unroll
            for (int e=0;e<8;++e){
                int k=32*s+8*g4+e;
                float v=0.f;
                if (k<F)        v=Wi[(size_t)j*F+k];
                else if (k-F<H) v=Wh[(size_t)j*H+(k-F)];
                f[e]=(f16)v;
            }
            Bf[q][s]=f;
        }
    }
    float bq[4];
#pragma unroll
    for (int q=0;q<4;++q) bq[q]=bi[96*q+u]+bh[96*q+u];

    float c4[4]={0.f,0.f,0.f,0.f};
    float h4[4]={0.f,0.f,0.f,0.f};
    float h4p[4]={0.f,0.f,0.f,0.f};              // h(t-1) for delayed ys store

    // staging maps
    const int xr=tid/24, xk=tid-xr*24;           // IS_L0: 16 rows x 24 feats
    const float* xbase = IS_L0 ? x + (size_t)(row0+xr)*(T_STEPS*24) + xk : nullptr;
    const int xoff = xr*KPB + ((xk*2)^((xr&7)<<4));

    const int yi=tid*4, yr=yi/H, yk=yi-yr*H;     // else: 16 rows x 96 halves
    const f16* ybase = (!IS_L0) ? ys + (size_t)(row0+yr)*H + yk : nullptr;
    const int yoff = yr*KPB + ((yk*2)^((yr&7)<<4));

    // stage t=0 into buffer 0
    if constexpr (IS_L0){
        float v=xbase[0];
        f16 vh=(f16)v, vl=(f16)(v-(float)vh);
        *(f16*)((char*)sh+xoff)=vh; *(f16*)((char*)sl+xoff)=vl;
    } else {
        uint2 v=*(const uint2*)(ybase);
        *(uint2*)((char*)sh+yoff)=v;
    }
    __syncthreads();

    const int aswz=(j15&7)<<4;
    const int abase=j15*KPB;

#pragma unroll 1
    for (int t=0;t<T_STEPS;++t){
        const int cur=t&1, nxt=cur^1;
        const f16* ch=sh+cur*BUF;
        const f16* cl=HAS_LO ? sl+cur*BUF : nullptr;
        f16*       nh=sh+nxt*BUF;
        f16*       nl=HAS_LO ? sl+nxt*BUF : nullptr;

        // T14: issue next-step global input load now; consumed at step end
        float xv=0.f; uint2 yv={0u,0u};
        if (t+1<T_STEPS){
            if constexpr (IS_L0) xv = xbase[(size_t)(t+1)*24];
            else                 yv = *(const uint2*)(ybase + (size_t)(t+1)*B_TOTAL*H);
        }
        // delayed ys store: h(t-1) from registers; drains with a full step of slack
        if constexpr (HAS_YSOUT){
            if (t>0){
#pragma unroll
                for (int r=0;r<4;++r)
                    ys[((size_t)(t-1)*B_TOTAL+row0+4*g4+r)*H+u]=(f16)h4p[r];
            }
        }

        // ---- gate GEMM: two accumulator chains per gate (slice parity) ----
        f32x4 acch[4], accl[4];
#pragma unroll
        for (int q=0;q<4;++q){
            f32x4 a={bq[q],bq[q],bq[q],bq[q]}; acch[q]=a;
            f32x4 z={0.f,0.f,0.f,0.f};          accl[q]=z;
        }
#pragma unroll
        for (int s=0;s<KS;++s){
            int kb=((s*64+g4*16)^aswz);
            f16x8 ah=*(const f16x8*)((const char*)ch+abase+kb);
            if (s&1){
#pragma unroll
                for (int q=0;q<4;++q)
                    accl[q]=__builtin_amdgcn_mfma_f32_16x16x32_f16(ah,Bf[q][s],accl[q],0,0,0);
            } else {
#pragma unroll
                for (int q=0;q<4;++q)
                    acch[q]=__builtin_amdgcn_mfma_f32_16x16x32_f16(ah,Bf[q][s],acch[q],0,0,0);
            }
        }
        if constexpr (HAS_LO){  // x residual: slice 0 only
            int kb=((g4*16)^aswz);
            f16x8 al=*(const f16x8*)((const char*)cl+abase+kb);
#pragma unroll
            for (int q=0;q<4;++q)
                accl[q]=__builtin_amdgcn_mfma_f32_16x16x32_f16(al,Bf[q][0],accl[q],0,0,0);
        }
        // ---- cell update (registers) ----
#pragma unroll
        for (int r=0;r<4;++r){
            float iv=sigf(acch[0][r]+accl[0][r]);
            float fv=sigf(acch[1][r]+accl[1][r]);
            float gv=tanhf_(acch[2][r]+accl[2][r]);
            float ov=sigf(acch[3][r]+accl[3][r]);
            float c=fv*c4[r]+iv*gv;
            c4[r]=c;
            h4[r]=ov*tanhf_(c);
        }
        // ---- h (f16-only) -> buf[nxt]; hn/hsum at last step ----
#pragma unroll
        for (int r=0;r<4;++r){
            int row=4*g4+r, swz=(row&7)<<4;
            float h=h4[r];
            *(f16*)((char*)nh + row*KPB + (((F+u)*2)^swz)) = (f16)h;
            if constexpr (WRITE_HN){ if (t==T_STEPS-1) hn1g[(size_t)(row0+row)*H+u]=h; }
            if constexpr (IS_LAST) { if (t==T_STEPS-1) hsum[row*96+u]=h; }
            h4p[r]=h;
        }
        // ---- staged input -> buf[nxt] ----
        if (t+1<T_STEPS){
            if constexpr (IS_L0){
                f16 vh=(f16)xv, vl=(f16)(xv-(float)vh);
                *(f16*)((char*)nh+xoff)=vh; *(f16*)((char*)nl+xoff)=vl;
            } else {
                *(uint2*)((char*)nh+yoff)=yv;
            }
        }
        __syncthreads();   // the only barrier per step
    }
    // final delayed ys store (t = T-1)
    if constexpr (HAS_YSOUT){
#pragma unroll
        for (int r=0;r<4;++r)
            ys[((size_t)(T_STEPS-1)*B_TOTAL+row0+4*g4+r)*H+u]=(f16)h4p[r];
    }

    if constexpr (IS_LAST){
        // hsum = h3(T-1) + hn1 (global, from layer-1 kernel), then fused head
        {
            float4 v=*(const float4*)(hn1g + (size_t)row0*96 + tid*4);
            hsum[tid*4+0]+=v.x; hsum[tid*4+1]+=v.y;
            hsum[tid*4+2]+=v.z; hsum[tid*4+3]+=v.w;
        }
        __syncthreads();
        if (tid<256){
            int r=tid>>4, jj=tid&15;
            float a=fc1_b[jj];
            for (int uu=0;uu<96;++uu) a+=fc1_w[jj*96+uu]*fmaxf(hsum[r*96+uu],0.f);
            z1[r*16+jj]=fmaxf(a,0.f);
        }
        __syncthreads();
        if (tid<128){
            int r=tid>>3, jj=tid&7;
            float a=fc2_b[jj];
#pragma unroll
            for (int uu=0;uu<16;++uu) a+=fc2_w[jj*16+uu]*z1[r*16+uu];
            z2[r*8+jj]=fmaxf(a,0.f);
        }
        __syncthreads();
        if (tid<16){
            float a=fc3_b[0];
#pragma unroll
            for (int uu=0;uu<8;++uu) a+=fc3_w[uu]*z2[tid*8+uu];
            out[row0+tid]=a;
        }
    }
}

extern "C" void kernel_launch(void* const* d_in, const int* in_sizes, int n_in,
                              void* d_out, int out_size, void* d_ws, size_t ws_size,
                              hipStream_t stream) {
    const float* x         = (const float*)d_in[0];
    const float* W_ih0     = (const float*)d_in[1];
    const float* W_ih_rest = (const float*)d_in[2];
    const float* W_hh      = (const float*)d_in[3];
    const float* b_ih      = (const float*)d_in[4];
    const float* b_hh      = (const float*)d_in[5];
    const float* fc1_w     = (const float*)d_in[6];
    const float* fc1_b     = (const float*)d_in[7];
    const float* fc2_w     = (const float*)d_in[8];
    const float* fc2_b     = (const float*)d_in[9];
    const float* fc3_w     = (const float*)d_in[10];
    const float* fc3_b     = (const float*)d_in[11];
    float* out = (float*)d_out;

    const size_t YS = (size_t)T_STEPS * B_TOTAL * H * sizeof(f16);   // ~100.7 MB
    const size_t HN = (size_t)B_TOTAL * H * sizeof(float);           // ~1.6 MB
    if (ws_size < YS + HN) {
        hipMemsetAsync(d_out, 0, (size_t)out_size * sizeof(float), stream);
        return;
    }
    f16*   ys   = (f16*)d_ws;
    float* hn1g = (float*)((char*)d_ws + YS);

    const int GH = 384 * 96;

    // layer 0: x -> ys
    lstm_seq<24, true,  true,  false, false><<<NBLK, NTH, 0, stream>>>(
        x, ys, W_ih0, W_hh, b_ih, b_hh, hn1g,
        fc1_w, fc1_b, fc2_w, fc2_b, fc3_w, fc3_b, out);
    // layer 1: ys -> ys (in-place), hn1 -> global
    lstm_seq<96, false, true,  true,  false><<<NBLK, NTH, 0, stream>>>(
        nullptr, ys, W_ih_rest,        W_hh + 1*GH, b_ih + 1*384, b_hh + 1*384, hn1g,
        fc1_w, fc1_b, fc2_w, fc2_b, fc3_w, fc3_b, out);
    // layer 2: ys -> ys
    lstm_seq<96, false, true,  false, false><<<NBLK, NTH, 0, stream>>>(
        nullptr, ys, W_ih_rest + 1*GH, W_hh + 2*GH, b_ih + 2*384, b_hh + 2*384, hn1g,
        fc1_w, fc1_b, fc2_w, fc2_b, fc3_w, fc3_b, out);
    // layer 3: ys -> (head fused) -> out
    lstm_seq<96, false, false, false, true ><<<NBLK, NTH, 0, stream>>>(
        nullptr, ys, W_ih_rest + 2*GH, W_hh + 3*GH, b_ih + 3*384, b_hh + 3*384, hn1g,
        fc1_w, fc1_b, fc2_w, fc2_b, fc3_w, fc3_b, out);
}